// Round 17
// baseline (842.380 us; speedup 1.0000x reference)
//
#include <hip/hip_runtime.h>

// SOM vector-quantizer fused kernel for MI355X (gfx950).
// Outputs (flat in d_out): [0] loss scalar, [1 .. 8388608] quantized_st
// in [B,C,D,H,W] layout, [8388609 ..] one-hot encodings [N,256].
//
// N = 262144 voxels, EMB_D = 32, K = 256 (16x16 SOM grid).
//
// R12 (resubmit; round-16 container failure, never measured):
//  * R11 (ILP=4) measured NULL vs R10 (~363 vs ~362 normalized) -> the
//    scan is NOT dependency-latency-bound. R9 counters: VALUBusy 68%,
//    Occupancy 34% -- occupancy is structurally capped at 16 waves/CU by
//    one-thread-per-voxel (4096 waves). The scan's 76us = ~31us VALU
//    floor / utilization. Only more waves fixes it.
//  * THE CHANGE: 2 threads per voxel (512-thr blocks, 8192 waves,
//    32 waves/CU). Lane pair (2i, 2i+1): even scans k=0..127, odd
//    k=128..255; merge via ONE __shfl_xor -- same wave, NO post-scan
//    barrier (R8's vmcnt-drain trap avoided). Cross-half tie keeps the
//    lower half -> argmin exactly equals the full ascending scan.
//  * LDS wl dropped (LDS = 1KB wsql) so 4 blocks x 8 waves fit per CU;
//    launch_bounds(512,8) pins VGPR<=64 (R11 used 60). Post-scan gathers
//    (commit row + som neighbors) read W from global (L1-resident 32KB,
//    same floats, same fmaf order). R3~R4~R5 proved delivery mechanism
//    is cost-equal, so per-lane VMEM in the scan is fine.
//  * Tail pair-split: even lane stores out c=0..15 + neighbors {up,down}
//    + the 1.0; odd stores c=16..31 + {left,right}. Per-voxel tensor
//    outputs bit-exact; only the tolerance-checked scalar loss's sum
//    association changes (precedent: R2->R3 slot restructure passed).
//  * R10's post-barrier wave-private enc zeroing kept (32 rows/wave).

#define SOM_K      256
#define EMB_D      32
#define N_VOX      262144
#define SPATIAL    32768          // 32*32*32 per batch
#define OUT_ELEMS  8388608        // 8*32*32768
#define COMMIT_DEN 8388608.0f
#define NSLOT      256            // loss accumulator slots (64B apart)

// ---------------------------------------------------------------------------
// prep: zero the slot accumulators (ws is poisoned to 0xAA every launch).
// ---------------------------------------------------------------------------
__global__ __launch_bounds__(256) void som_prep_kernel(float* __restrict__ ws) {
  float4* p = (float4*)ws;               // 256 slots * 16 floats = 1024 float4
  int t = threadIdx.x;
#pragma unroll
  for (int i = 0; i < 4; ++i) p[i * 256 + t] = make_float4(0.f, 0.f, 0.f, 0.f);
}

// ---------------------------------------------------------------------------
// main fused kernel: 1024 blocks x 512 threads, TWO threads per voxel.
// ---------------------------------------------------------------------------
__global__ __launch_bounds__(512, 8) void som_main_kernel(
    const float* __restrict__ x,     // [8,32,32,32,32]
    const float* __restrict__ w,     // [256,32]
    float* __restrict__ slots,       // ws: NSLOT x 16 floats
    float* __restrict__ out,         // d_out+1, [8,32,32768]
    float* __restrict__ enc) {       // d_out+1+OUT_ELEMS, [N,256]
  __shared__ __align__(16) float wsql[SOM_K];   // ||W_k||^2

  const int t    = threadIdx.x;
  const int half = t & 1;              // 0: k 0..127, 1: k 128..255
  const int vloc = t >> 1;             // voxel index within block, 0..255
  const int n    = blockIdx.x * 256 + vloc;
  const int base = (n >> 15) * (EMB_D * SPATIAL) + (n & (SPATIAL - 1));

  // Voxel load (both pair lanes load the same 32 values; TA coalesces the
  // duplicated addresses; needed by both halves' dot chains + xsq).
  float xv[EMB_D];
#pragma unroll
  for (int c = 0; c < EMB_D; ++c) xv[c] = x[base + c * SPATIAL];

  // ||W_t||^2 -- one row per thread t<256, from global w, EXACT sequential
  // fmaf order c=0..31 as R1..R11 (bit-identical values).
  if (t < SOM_K) {
    float s = 0.0f;
#pragma unroll
    for (int c = 0; c < EMB_D; ++c) {
      float v = w[t * EMB_D + c];
      s = fmaf(v, v, s);
    }
    wsql[t] = s;
  }

  float xsq = 0.0f;
#pragma unroll
  for (int c = 0; c < EMB_D; ++c) xsq = fmaf(xv[c], xv[c], xsq);
  __syncthreads();   // wsql ready. ONLY barrier in the kernel.

  // Wave-private enc pre-zero AFTER the barrier (R10): wave owns voxels
  // [blk*256 + wave*32, +32) -> 8192 floats at float-offset == 1 mod 4.
  // Lead 3 + 2047 aligned float4 + tail 1. Fire-and-forget: drains on the
  // VMEM pipe underneath the scan.
  {
    const int lane = t & 63, wave = t >> 6;            // wave 0..7
    float* rb = enc + (size_t)(blockIdx.x * 256 + wave * 32) * SOM_K;
    float4* rb4 = (float4*)(rb + 3);
    const float4 z4 = make_float4(0.f, 0.f, 0.f, 0.f);
    for (int r = 0; r < 32; ++r) {
      int idx = r * 64 + lane;
      if (idx < 2047) rb4[idx] = z4;
    }
    if (lane == 0)       { rb[0] = 0.f; rb[1] = 0.f; rb[2] = 0.f; }
    else if (lane == 63) { rb[8191] = 0.f; }
  }

  // Half-range distance scan: this thread covers k in [klo, klo+128).
  // Per-k arithmetic identical to R1..R11: sequential fmaf j=0..31,
  // d=(xsq+wsql[k])-2*dot, ascending-k strict-< compares.
  const int klo = half << 7;
  const float* __restrict__ wrb = w + (klo << 5);      // base of this half
  const float4* wsq4 = (const float4*)wsql;
  float best = 3.402823466e38f;
  int   bidx = klo;
#pragma unroll 1
  for (int k = 0; k < 128; k += 4) {
    const float* r0 = wrb + (k << 5);
    const float* r1 = r0 + 32;
    const float* r2 = r0 + 64;
    const float* r3 = r0 + 96;
    float d0 = 0.0f, d1 = 0.0f, d2 = 0.0f, d3 = 0.0f;
#pragma unroll
    for (int j = 0; j < EMB_D; ++j) {
      const float xj = xv[j];
      d0 = fmaf(r0[j], xj, d0);
      d1 = fmaf(r1[j], xj, d1);
      d2 = fmaf(r2[j], xj, d2);
      d3 = fmaf(r3[j], xj, d3);
    }
    const float4 ws4 = wsq4[(klo + k) >> 2];
    const float e0 = (xsq + ws4.x) - 2.0f * d0;        // same rounding order
    const float e1 = (xsq + ws4.y) - 2.0f * d1;
    const float e2 = (xsq + ws4.z) - 2.0f * d2;
    const float e3 = (xsq + ws4.w) - 2.0f * d3;
    if (e0 < best) { best = e0; bidx = klo + k;     }
    if (e1 < best) { best = e1; bidx = klo + k + 1; }
    if (e2 < best) { best = e2; bidx = klo + k + 2; }
    if (e3 < best) { best = e3; bidx = klo + k + 3; }
  }

  // Pair merge: both lanes end with the full-range argmin. Rule: take the
  // HIGH half iff e_hi < e_lo (ties -> low half == lower k), exactly the
  // sequential ascending scan's tie behavior.
  {
    const float eo = __shfl_xor(best, 1, 64);
    const int   ko = __shfl_xor(bidx, 1, 64);
    if (half == 0) { if (eo < best)    { best = eo; bidx = ko; } }
    else           { if (!(best < eo)) { best = eo; bidx = ko; } }
  }

  // This wave's zero stores retired under the scan; seal same-address
  // ordering, then the even lane writes the voxel's single 1.0.
  asm volatile("s_waitcnt vmcnt(0)" ::: "memory");
  if (half == 0) enc[(size_t)n * SOM_K + bidx] = 1.0f;

  // Quantized output + commitment partial, pair-split: even lane handles
  // c=0..15, odd c=16..31. W row read from global (same floats as the old
  // LDS copy; L1-resident). Same per-element arithmetic.
  float commit = 0.0f;
  {
    const float4* wv4  = (const float4*)w;
    const float4* qrow = wv4 + (bidx << 3);            // 8 float4 per row
    const int j0 = half * 4;
#pragma unroll
    for (int jj = 0; jj < 4; ++jj) {
      const int j = j0 + jj;
      float4 q = qrow[j];
      float qq[4] = { q.x, q.y, q.z, q.w };
#pragma unroll
      for (int u = 0; u < 4; ++u) {
        int c = 4 * j + u;
        out[base + c * SPATIAL] = qq[u];               // coalesced dword
        float df = qq[u] - xv[c];
        commit = fmaf(df, df, commit);
      }
    }
  }

  // SOM loss, pair-split: even lane takes BMU term + {up,down}; odd takes
  // {left,right}. Per-neighbor arithmetic unchanged.
  float som = (half == 0) ? best : 0.0f;
  float cnt = (half == 0) ? 1.0f : 0.0f;
  {
    const int h   = bidx >> 4;
    const int wc2 = bidx & 15;
    int   cand[2];
    float valid[2];
    if (half == 0) {
      cand[0] = bidx - 16; valid[0] = h > 0  ? 1.f : 0.f;
      cand[1] = bidx + 16; valid[1] = h < 15 ? 1.f : 0.f;
    } else {
      cand[0] = bidx - 1;  valid[0] = wc2 > 0  ? 1.f : 0.f;
      cand[1] = bidx + 1;  valid[1] = wc2 < 15 ? 1.f : 0.f;
    }
    const float4* wv4 = (const float4*)w;
#pragma unroll
    for (int j = 0; j < 2; ++j) {
      int nk = valid[j] != 0.0f ? cand[j] : bidx;      // clamp (masked)
      const float4* nrow = wv4 + (nk << 3);
      float dot = 0.0f;
#pragma unroll
      for (int jj = 0; jj < 8; ++jj) {
        float4 q = nrow[jj];
        dot = fmaf(q.x, xv[4 * jj + 0], dot);
        dot = fmaf(q.y, xv[4 * jj + 1], dot);
        dot = fmaf(q.z, xv[4 * jj + 2], dot);
        dot = fmaf(q.w, xv[4 * jj + 3], dot);
      }
      float d = (xsq + wsql[nk]) - 2.0f * dot;
      som = fmaf(valid[j], d, som);
      cnt += valid[j];
    }
  }

  // Wave reduction (covers 32 voxels' full contributions -- both pair
  // lanes are in-wave) -> 3 atomics per wave into this block's slot.
  for (int off = 32; off > 0; off >>= 1) {
    commit += __shfl_down(commit, off, 64);
    som    += __shfl_down(som,    off, 64);
    cnt    += __shfl_down(cnt,    off, 64);
  }
  if ((t & 63) == 0) {
    float* sp = slots + (size_t)(blockIdx.x & (NSLOT - 1)) * 16;
    atomicAdd(sp + 0, commit);
    atomicAdd(sp + 1, som);
    atomicAdd(sp + 2, cnt);
  }
}

// ---------------------------------------------------------------------------
// final: reduce the 256 slots with one wave.
// ---------------------------------------------------------------------------
__global__ __launch_bounds__(64) void som_final_kernel(
    const float* __restrict__ slots, float* __restrict__ loss) {
  const int t = threadIdx.x;           // one wave
  float commit = 0.f, som = 0.f, cnt = 0.f;
#pragma unroll
  for (int i = 0; i < 4; ++i) {
    const float* sp = slots + (size_t)(i * 64 + t) * 16;
    commit += sp[0]; som += sp[1]; cnt += sp[2];
  }
  for (int off = 32; off > 0; off >>= 1) {
    commit += __shfl_down(commit, off, 64);
    som    += __shfl_down(som,    off, 64);
    cnt    += __shfl_down(cnt,    off, 64);
  }
  if (t == 0) loss[0] = 6.0f * (commit / COMMIT_DEN) + som / cnt;
}

extern "C" void kernel_launch(void* const* d_in, const int* in_sizes, int n_in,
                              void* d_out, int out_size, void* d_ws, size_t ws_size,
                              hipStream_t stream) {
  const float* x = (const float*)d_in[0];   // [8,32,32,32,32]
  const float* w = (const float*)d_in[1];   // [256,32]
  float* ws  = (float*)d_ws;                // NSLOT x 16 float slots
  float* o   = (float*)d_out;               // [0] loss, then out, then enc

  som_prep_kernel<<<1, 256, 0, stream>>>(ws);
  som_main_kernel<<<N_VOX / 256, 512, 0, stream>>>(
      x, w, ws, o + 1, o + 1 + OUT_ELEMS);
  som_final_kernel<<<1, 64, 0, stream>>>(ws, o);
}

// Round 18
// 426.269 us; speedup vs baseline: 1.9762x; 1.9762x over previous
//
#include <hip/hip_runtime.h>

// SOM vector-quantizer fused kernel for MI355X (gfx950).
// Outputs (flat in d_out): [0] loss scalar, [1 .. 8388608] quantized_st
// in [B,C,D,H,W] layout, [8388609 ..] one-hot encodings [N,256].
//
// N = 262144 voxels, EMB_D = 32, K = 256 (16x16 SOM grid).
//
// R12 -> R13 (wave-uniform split-K; fixes R12's two fatal mechanisms):
//  * R12 post-mortem: main 585us, VALUBusy 12.5%, FETCH 87MB, VGPR=32
//    with xv[32] in source. (1) lane-interleaved half (t&1) made the W
//    row index wave-DIVERGENT -> s_load scalarization lost, scan went
//    per-lane VMEM latency-bound. (2) launch_bounds(512,8)'s 64-VGPR cap
//    + ILP4 demoted xv to reloads (FETCH surge).
//  * THE FIX: split K across WAVES. Waves 0..3 scan k=0..127, waves 4..7
//    scan k=128..255; 'wave' forced uniform via readfirstlane -> klo in
//    SGPR -> AS4 s_load delivery preserved (R5/R10 mechanism). Pair
//    (wave w, w+4) shares voxel vloc=(w&3)*64+lane; merge via LDS +
//    ONE barrier. That barrier also orders the enc zero stream before
//    the 1.0 stores across waves (per-wave vmcnt(0) + sync).
//  * ILP-2 scan (R11: ILP null) + launch_bounds(512,6) (~80 VGPR cap,
//    no demotion risk; actual ~55 -> runtime can still reach 8 waves/SIMD
//    = 32 waves/CU, 2x the one-thread-per-voxel cap R9 measured at 34%).
//  * wl LDS restored for the divergent gathers; LDS/block = 39.9KB ->
//    exactly 4 x 512-thread blocks per CU.
//  * Tail = R10's proven structure, executed by half-0 threads (identical
//    vloc->lane mapping/coalescing); half-1 waves retire post-merge.
//  * Per-voxel tensor outputs bit-exact (same fmaf orders; cross-half tie
//    keeps lower k). Only the loss's tolerance-checked sum association
//    changes (R2->R3 precedent passed).

#define SOM_K      256
#define EMB_D      32
#define WPAD       36             // LDS row stride (floats): 16B-aligned rows
#define N_VOX      262144
#define SPATIAL    32768          // 32*32*32 per batch
#define OUT_ELEMS  8388608        // 8*32*32768
#define COMMIT_DEN 8388608.0f
#define NSLOT      256            // loss accumulator slots (64B apart)

#define CONST_AS __attribute__((address_space(4)))

// ---------------------------------------------------------------------------
// prep: zero the slot accumulators (ws is poisoned to 0xAA every launch).
// ---------------------------------------------------------------------------
__global__ __launch_bounds__(256) void som_prep_kernel(float* __restrict__ ws) {
  float4* p = (float4*)ws;               // 256 slots * 16 floats = 1024 float4
  int t = threadIdx.x;
#pragma unroll
  for (int i = 0; i < 4; ++i) p[i * 256 + t] = make_float4(0.f, 0.f, 0.f, 0.f);
}

// ---------------------------------------------------------------------------
// main fused kernel: 1024 blocks x 512 threads; waves 0..3 = K-half 0,
// waves 4..7 = K-half 1; wave pair (w, w+4) covers the same 64 voxels.
// ---------------------------------------------------------------------------
__global__ __launch_bounds__(512, 6) void som_main_kernel(
    const float* __restrict__ x,     // [8,32,32,32,32]
    const float* __restrict__ w,     // [256,32]
    float* __restrict__ slots,       // ws: NSLOT x 16 floats
    float* __restrict__ out,         // d_out+1, [8,32,32768]
    float* __restrict__ enc) {       // d_out+1+OUT_ELEMS, [N,256]
  __shared__ __align__(16) float wl[SOM_K * WPAD];   // 36.9 KB
  __shared__ __align__(16) float wsql[SOM_K];        // 1 KB
  __shared__ float sbest[256];                       // 1 KB (half-1 results)
  __shared__ int   sbidx[256];                       // 1 KB

  const int t    = threadIdx.x;
  const int lane = t & 63;
  const int wave = __builtin_amdgcn_readfirstlane(t >> 6);  // SGPR, 0..7
  const int half = wave >> 2;                               // SGPR, 0/1
  const int vloc = ((wave & 3) << 6) + lane;                // voxel in block
  const int n    = blockIdx.x * 256 + vloc;
  const int base = (n >> 15) * (EMB_D * SPATIAL) + (n & (SPATIAL - 1));

  const CONST_AS float* wcp = (const CONST_AS float*)(unsigned long long)w;

  // Voxel load first (both half-waves load their voxel's 32 values; the
  // duplicate read of x is L2-absorbed, +33MB fetch, acceptable).
  float xv[EMB_D];
#pragma unroll
  for (int c = 0; c < EMB_D; ++c) xv[c] = x[base + c * SPATIAL];

  // Stage W -> LDS (coalesced read, padded scatter write; 16 elems/thread).
#pragma unroll
  for (int i = 0; i < 16; ++i) {
    int e = i * 512 + t;             // 0..8191
    int r = e >> 5, c = e & 31;
    wl[r * WPAD + c] = w[e];
  }
  __syncthreads();   // wl ready

  // ||W_t||^2 from the LDS copy -- same sequential fmaf order as R1..R11.
  if (t < SOM_K) {
    const float4* row = (const float4*)(wl + t * WPAD);
    float s = 0.0f;
#pragma unroll
    for (int j = 0; j < 8; ++j) {
      float4 q = row[j];
      s = fmaf(q.x, q.x, s);
      s = fmaf(q.y, q.y, s);
      s = fmaf(q.z, q.z, s);
      s = fmaf(q.w, q.w, s);
    }
    wsql[t] = s;
  }

  float xsq = 0.0f;
#pragma unroll
  for (int c = 0; c < EMB_D; ++c) xsq = fmaf(xv[c], xv[c], xsq);
  __syncthreads();   // wsql ready. Last barrier BEFORE the scan.

  // Wave-private enc pre-zero AFTER the pre-scan barriers (R10 lesson):
  // wave owns voxels [blk*256 + wave*32, +32) -> 8192 floats at float
  // offset == 1 mod 4. Lead 3 + 2047 aligned float4 + tail 1. The stores
  // drain on the VMEM pipe underneath the scan; the post-scan merge
  // barrier (per-wave vmcnt(0)+sync) orders them before any 1.0 store.
  {
    float* rb = enc + (size_t)(blockIdx.x * 256 + wave * 32) * SOM_K;
    float4* rb4 = (float4*)(rb + 3);
    const float4 z4 = make_float4(0.f, 0.f, 0.f, 0.f);
    for (int r = 0; r < 32; ++r) {
      int idx = r * 64 + lane;
      if (idx < 2047) rb4[idx] = z4;
    }
    if (lane == 0)       { rb[0] = 0.f; rb[1] = 0.f; rb[2] = 0.f; }
    else if (lane == 63) { rb[8191] = 0.f; }
  }

  // Half-range distance scan: this wave covers k in [klo, klo+128).
  // klo is SGPR-uniform -> wr addresses are uniform -> s_load delivery.
  // Per-k arithmetic identical to R1..R11 (sequential fmaf j=0..31,
  // d=(xsq+wsql[k])-2*dot, ascending-k strict-< compares). ILP-2.
  const int klo = half << 7;
  float best = 3.402823466e38f;
  int   bidx = klo;
#pragma unroll 1
  for (int k2 = 0; k2 < 128; k2 += 2) {
    const CONST_AS float* r0 = wcp + ((klo + k2) << 5);
    const CONST_AS float* r1 = r0 + 32;
    float d0 = 0.0f, d1 = 0.0f;
#pragma unroll
    for (int j = 0; j < EMB_D; ++j) {
      const float xj = xv[j];
      d0 = fmaf(r0[j], xj, d0);
      d1 = fmaf(r1[j], xj, d1);
    }
    const float e0 = (xsq + wsql[klo + k2])     - 2.0f * d0;  // same order
    const float e1 = (xsq + wsql[klo + k2 + 1]) - 2.0f * d1;
    if (e0 < best) { best = e0; bidx = klo + k2;     }
    if (e1 < best) { best = e1; bidx = klo + k2 + 1; }
  }

  // Publish half-1 results; merge barrier (also drains the zero stores).
  if (half == 1) { sbest[vloc] = best; sbidx[vloc] = bidx; }
  __syncthreads();
  if (half == 1) return;     // half-1 waves done (no barriers follow)

  // Merge: take the high half iff strictly smaller (tie -> lower k),
  // exactly the sequential ascending scan's behavior.
  {
    const float s1 = sbest[vloc];
    const int   k1 = sbidx[vloc];
    if (s1 < best) { best = s1; bidx = k1; }
  }

  // One-hot 1.0 (zeros ordered by the merge barrier).
  enc[(size_t)n * SOM_K + bidx] = 1.0f;

  // Quantized output + commitment-loss partial (gather row bidx from LDS).
  float commit = 0.0f;
  {
    const float4* qrow = (const float4*)(wl + bidx * WPAD);
#pragma unroll
    for (int j = 0; j < 8; ++j) {
      float4 q = qrow[j];
      float qq[4] = { q.x, q.y, q.z, q.w };
#pragma unroll
      for (int u = 0; u < 4; ++u) {
        int c = 4 * j + u;
        out[base + c * SPATIAL] = qq[u];     // coalesced dword store
        float df = qq[u] - xv[c];
        commit = fmaf(df, df, commit);
      }
    }
  }

  // SOM loss: dist to BMU + its up/down/left/right grid neighbors.
  float som = best;
  float cnt = 1.0f;
  {
    const int h   = bidx >> 4;
    const int wc2 = bidx & 15;
    const int   cand[4]  = { bidx - 16, bidx + 16, bidx - 1, bidx + 1 };
    const float valid[4] = { h > 0 ? 1.f : 0.f,  h < 15 ? 1.f : 0.f,
                             wc2 > 0 ? 1.f : 0.f, wc2 < 15 ? 1.f : 0.f };
#pragma unroll
    for (int j = 0; j < 4; ++j) {
      int nk = valid[j] != 0.0f ? cand[j] : bidx;   // clamp (masked anyway)
      const float4* nrow = (const float4*)(wl + nk * WPAD);
      float dot = 0.0f;
#pragma unroll
      for (int jj = 0; jj < 8; ++jj) {
        float4 q = nrow[jj];
        dot = fmaf(q.x, xv[4 * jj + 0], dot);
        dot = fmaf(q.y, xv[4 * jj + 1], dot);
        dot = fmaf(q.z, xv[4 * jj + 2], dot);
        dot = fmaf(q.w, xv[4 * jj + 3], dot);
      }
      float d = (xsq + wsql[nk]) - 2.0f * dot;
      som = fmaf(valid[j], d, som);
      cnt += valid[j];
    }
  }

  // Wave reduction (waves 0..3 hold all loss terms) -> 3 atomics/wave.
  for (int off = 32; off > 0; off >>= 1) {
    commit += __shfl_down(commit, off, 64);
    som    += __shfl_down(som,    off, 64);
    cnt    += __shfl_down(cnt,    off, 64);
  }
  if (lane == 0) {
    float* sp = slots + (size_t)(blockIdx.x & (NSLOT - 1)) * 16;
    atomicAdd(sp + 0, commit);
    atomicAdd(sp + 1, som);
    atomicAdd(sp + 2, cnt);
  }
}

// ---------------------------------------------------------------------------
// final: reduce the 256 slots with one wave.
// ---------------------------------------------------------------------------
__global__ __launch_bounds__(64) void som_final_kernel(
    const float* __restrict__ slots, float* __restrict__ loss) {
  const int t = threadIdx.x;           // one wave
  float commit = 0.f, som = 0.f, cnt = 0.f;
#pragma unroll
  for (int i = 0; i < 4; ++i) {
    const float* sp = slots + (size_t)(i * 64 + t) * 16;
    commit += sp[0]; som += sp[1]; cnt += sp[2];
  }
  for (int off = 32; off > 0; off >>= 1) {
    commit += __shfl_down(commit, off, 64);
    som    += __shfl_down(som,    off, 64);
    cnt    += __shfl_down(cnt,    off, 64);
  }
  if (t == 0) loss[0] = 6.0f * (commit / COMMIT_DEN) + som / cnt;
}

extern "C" void kernel_launch(void* const* d_in, const int* in_sizes, int n_in,
                              void* d_out, int out_size, void* d_ws, size_t ws_size,
                              hipStream_t stream) {
  const float* x = (const float*)d_in[0];   // [8,32,32,32,32]
  const float* w = (const float*)d_in[1];   // [256,32]
  float* ws  = (float*)d_ws;                // NSLOT x 16 float slots
  float* o   = (float*)d_out;               // [0] loss, then out, then enc

  som_prep_kernel<<<1, 256, 0, stream>>>(ws);
  som_main_kernel<<<N_VOX / 256, 512, 0, stream>>>(
      x, w, ws, o + 1, o + 1 + OUT_ELEMS);
  som_final_kernel<<<1, 64, 0, stream>>>(ws, o);
}